// Round 1
// baseline (61.632 us; speedup 1.0000x reference)
//
#include <hip/hip_runtime.h>
#include <hip/hip_bf16.h>

typedef __bf16 bf16x8 __attribute__((ext_vector_type(8)));
typedef __bf16 bf16x4 __attribute__((ext_vector_type(4)));
typedef float  f32x4  __attribute__((ext_vector_type(4)));

#define N_BASIS   512
#define FRAME_LEN 64
#define BATCH     8
#define FRAMES    16000
#define STEP      32
#define OUT_PER_BATCH (STEP * (FRAMES - 1) + FRAME_LEN)   // 512032

#define WAVES            8
#define BLOCK            (WAVES * 64)        // 512 threads
#define FRAMES_PER_BLOCK (WAVES * 16)        // 128
#define TILES_PER_BATCH  (FRAMES / FRAMES_PER_BLOCK)  // 125

// C[f][c] = sum_n weight[f][n] * W[c][n], then out[b][32*f + c] += C[f][c].
__global__ __launch_bounds__(BLOCK, 4)
void basis_ola_kernel(const float* __restrict__ weight,
                      const float* __restrict__ basis,
                      float* __restrict__ out)
{
    // W staged as bf16, XOR-swizzled to kill ds_read_b128 bank conflicts
    // (row stride 1KB -> all lanes same bank without the swizzle).
    __shared__ __bf16 Wlds[FRAME_LEN * N_BASIS];   // 64 KiB exactly

    const int tid = threadIdx.x;

    // ---- stage basis (64x512 f32 -> bf16 LDS), elem swizzle e ^= (c&7)<<3 ----
    for (int q = tid; q < (FRAME_LEN * N_BASIS) / 4; q += BLOCK) {
        const int e = q * 4;
        const int c = e >> 9;                        // row (output col), /512
        const float4 v = *(const float4*)(basis + e);
        bf16x4 b;
        b[0] = (__bf16)v.x; b[1] = (__bf16)v.y;
        b[2] = (__bf16)v.z; b[3] = (__bf16)v.w;
        const int se = e ^ ((c & 7) << 3);
        *(bf16x4*)(&Wlds[se]) = b;
    }
    __syncthreads();

    const int bb   = blockIdx.x / TILES_PER_BATCH;   // batch
    const int tile = blockIdx.x % TILES_PER_BATCH;
    const int F0   = tile * FRAMES_PER_BLOCK;

    const int wave = tid >> 6;
    const int lane = tid & 63;
    const int lo   = lane & 15;
    const int hi   = lane >> 4;

    // A-fragment row for this lane (mfma_f32_16x16x32_bf16: row = lane&15,
    // k = (lane>>4)*8 + j).
    const int frame_row = F0 + wave * 16 + lo;
    const float* arow = weight + ((size_t)bb * FRAMES + frame_row) * (size_t)N_BASIS;

    f32x4 acc[4] = {};   // nt = 0..3 -> columns nt*16 + lo

    #pragma unroll 2
    for (int ks = 0; ks < N_BASIS / 32; ++ks) {
        const int kk = ks * 32;

        const float4 a0 = *(const float4*)(arow + kk + hi * 8);
        const float4 a1 = *(const float4*)(arow + kk + hi * 8 + 4);
        bf16x8 af;
        af[0] = (__bf16)a0.x; af[1] = (__bf16)a0.y;
        af[2] = (__bf16)a0.z; af[3] = (__bf16)a0.w;
        af[4] = (__bf16)a1.x; af[5] = (__bf16)a1.y;
        af[6] = (__bf16)a1.z; af[7] = (__bf16)a1.w;

        #pragma unroll
        for (int nt = 0; nt < 4; ++nt) {
            const int c = nt * 16 + lo;
            int e = (c << 9) + kk + hi * 8;
            e ^= (c & 7) << 3;
            const bf16x8 bfr = *(const bf16x8*)(&Wlds[e]);
            acc[nt] = __builtin_amdgcn_mfma_f32_16x16x32_bf16(af, bfr, acc[nt], 0, 0, 0);
        }
    }

    // ---- fused overlap-and-add epilogue ----
    // acc[nt][r] = C[f][c], f = F0 + wave*16 + hi*4 + r, c = nt*16 + lo.
    // out[32f + c] has exactly two contributors: (f,c) and (f-1,c+32).
    // For c<32, r>=1 the partner (f-1, c+32) = acc[nt+2][r-1] lives in THIS
    // thread -> merged plain store. Edges (r==0 with c<32, r==3 with c>=32)
    // use atomicAdd onto the memset-zeroed output.
    float* ob = out + (size_t)bb * OUT_PER_BATCH;
    const int fbase = F0 + wave * 16 + hi * 4;

    #pragma unroll
    for (int nt = 0; nt < 2; ++nt) {
        // r == 0: partner lives in another thread/block
        atomicAdd(&ob[32 * fbase + nt * 16 + lo], acc[nt][0]);
        #pragma unroll
        for (int r = 1; r < 4; ++r) {
            const int t = 32 * (fbase + r) + nt * 16 + lo;
            ob[t] = acc[nt][r] + acc[nt + 2][r - 1];
        }
        // trailing partner-less value: (f = fbase+3, c = (nt+2)*16 + lo)
        const int t3 = 32 * (fbase + 3) + (nt + 2) * 16 + lo;
        atomicAdd(&ob[t3], acc[nt + 2][3]);
    }
}

extern "C" void kernel_launch(void* const* d_in, const int* in_sizes, int n_in,
                              void* d_out, int out_size, void* d_ws, size_t ws_size,
                              hipStream_t stream) {
    const float* weight = (const float*)d_in[0];   // (8, 16000, 512) f32
    const float* basis  = (const float*)d_in[1];   // (64, 512) f32
    float* out = (float*)d_out;                    // (8, 512032) f32

    // zero output: atomics accumulate onto it
    hipMemsetAsync(out, 0, (size_t)out_size * sizeof(float), stream);

    const int grid = BATCH * TILES_PER_BATCH;      // 1000 blocks
    basis_ola_kernel<<<grid, BLOCK, 0, stream>>>(weight, basis, out);
}

// Round 2
// 55.296 us; speedup vs baseline: 1.1146x; 1.1146x over previous
//
#include <hip/hip_runtime.h>
#include <hip/hip_bf16.h>

typedef __bf16 bf16x8 __attribute__((ext_vector_type(8)));
typedef __bf16 bf16x4 __attribute__((ext_vector_type(4)));
typedef float  f32x4  __attribute__((ext_vector_type(4)));

#define N_BASIS   512
#define FRAME_LEN 64
#define BATCH     8
#define FRAMES    16000
#define STEP      32
#define OUT_PER_BATCH (STEP * (FRAMES - 1) + FRAME_LEN)   // 512032

#define WAVES            8
#define BLOCK            (WAVES * 64)                 // 512 threads
#define FPB              (WAVES * 16)                 // frames per tile = 128
#define TPBATCH          (FRAMES / FPB)               // 125 tiles per batch
#define TOTAL_TILES      (BATCH * TPBATCH)            // 1000
#define TILES_PER_BLOCK  2
#define GRID             (TOTAL_TILES / TILES_PER_BLOCK)  // 500

// C[f][c] = sum_n weight[f][n] * W[c][n]; out[b][32f + c] = C[f][c] + C[f-1][c+32].
// Every output sample is written by exactly ONE plain store:
//   - thread-local merge for r>=1 (partner acc[nt+2][r-1] in same thread)
//   - __shfl_up(16) for r==0, hi>=1 (partner in lane-16)
//   - LDS exchange xbuf for r==0, hi==0 (partner in previous wave / previous tile)
//   - VALU-computed carry row for the block's first tile boundary
__global__ __launch_bounds__(BLOCK, 4)
void basis_ola_kernel(const float* __restrict__ weight,
                      const float* __restrict__ basis,
                      float* __restrict__ out)
{
    // basis as bf16, XOR-swizzled (row stride 1KB would be fully bank-conflicted)
    __shared__ __bf16 Wlds[FRAME_LEN * N_BASIS];      // 64 KiB
    // cross-wave / cross-tile OLA exchange, double-buffered by tile parity
    __shared__ float xbuf[2][WAVES][2][16];           // 2 KiB

    const int tid = threadIdx.x;

    // ---- stage basis (64x512 f32 -> bf16 LDS), elem swizzle e ^= (c&7)<<3 ----
    for (int q = tid; q < (FRAME_LEN * N_BASIS) / 4; q += BLOCK) {
        const int e = q * 4;
        const int c = e >> 9;
        const float4 v = *(const float4*)(basis + e);
        bf16x4 b;
        b[0] = (__bf16)v.x; b[1] = (__bf16)v.y;
        b[2] = (__bf16)v.z; b[3] = (__bf16)v.w;
        *(bf16x4*)(&Wlds[e ^ ((c & 7) << 3)]) = b;
    }
    __syncthreads();

    const int wave = tid >> 6;
    const int lane = tid & 63;
    const int lo   = lane & 15;
    const int hi   = lane >> 4;

    const int g0 = blockIdx.x * TILES_PER_BLOCK;

    // ---- pre-compute carry for the block's FIRST tile boundary ----
    // xbuf[1][7][nt][lo] must hold C[F0-1][16*(nt+2)+lo] for tile g0.
    // (consumed at ti==0 epilogue; zero if g0 is the first tile of a batch)
    if (wave == 0) {
        const int bb0 = g0 / TPBATCH, t0 = g0 % TPBATCH;
        float val = 0.f;
        if (t0 > 0) {
            const int c  = 32 + (lane >> 1);          // basis row 32..63
            const int kh = (lane & 1) * 256;          // half of K per lane
            const float* wr = weight + ((size_t)bb0 * FRAMES + (size_t)t0 * FPB - 1) * N_BASIS;
            for (int n = kh; n < kh + 256; n += 8) {
                const float4 a0 = *(const float4*)(wr + n);
                const float4 a1 = *(const float4*)(wr + n + 4);
                const int e = ((c << 9) + n) ^ ((c & 7) << 3);
                const bf16x8 bw = *(const bf16x8*)(&Wlds[e]);
                val += a0.x*(float)bw[0] + a0.y*(float)bw[1] + a0.z*(float)bw[2] + a0.w*(float)bw[3]
                     + a1.x*(float)bw[4] + a1.y*(float)bw[5] + a1.z*(float)bw[6] + a1.w*(float)bw[7];
            }
        }
        val += __shfl_xor(val, 1);
        if ((lane & 1) == 0) {
            const int cc = lane >> 1;                 // 0..31  (c-32)
            xbuf[1][WAVES - 1][cc >> 4][cc & 15] = val;
        }
    }

    for (int ti = 0; ti < TILES_PER_BLOCK; ++ti) {
        const int g    = g0 + ti;
        const int bb   = g / TPBATCH;
        const int tile = g % TPBATCH;
        const int F0   = tile * FPB;
        const int p    = ti & 1;

        // A-fragment row (mfma_f32_16x16x32_bf16: row = lane&15, k = (lane>>4)*8 + j)
        const float* arow = weight +
            ((size_t)bb * FRAMES + F0 + wave * 16 + lo) * (size_t)N_BASIS;

        f32x4 acc[4] = {};   // nt -> columns nt*16 + lo

        #pragma unroll 2
        for (int ks = 0; ks < N_BASIS / 32; ++ks) {
            const int kk = ks * 32;
            const float4 a0 = *(const float4*)(arow + kk + hi * 8);
            const float4 a1 = *(const float4*)(arow + kk + hi * 8 + 4);
            bf16x8 af;
            af[0] = (__bf16)a0.x; af[1] = (__bf16)a0.y;
            af[2] = (__bf16)a0.z; af[3] = (__bf16)a0.w;
            af[4] = (__bf16)a1.x; af[5] = (__bf16)a1.y;
            af[6] = (__bf16)a1.z; af[7] = (__bf16)a1.w;

            #pragma unroll
            for (int nt = 0; nt < 4; ++nt) {
                const int c = nt * 16 + lo;
                int e = (c << 9) + kk + hi * 8;
                e ^= (c & 7) << 3;
                const bf16x8 bfr = *(const bf16x8*)(&Wlds[e]);
                acc[nt] = __builtin_amdgcn_mfma_f32_16x16x32_bf16(af, bfr, acc[nt], 0, 0, 0);
            }
        }

        // ---- exchange: hi==3 lanes publish their trailing values ----
        // acc[nt+2][3] = C[F0+16w+15][16*(nt+2)+lo]
        if (hi == 3) {
            xbuf[p][wave][0][lo] = acc[2][3];
            xbuf[p][wave][1][lo] = acc[3][3];
        }
        __syncthreads();

        // ---- fused OLA epilogue, plain stores only ----
        float* ob = out + (size_t)bb * OUT_PER_BATCH;
        const int fbase = F0 + wave * 16 + hi * 4;

        #pragma unroll
        for (int nt = 0; nt < 2; ++nt) {
            // r == 0: partner C[fbase-1][16*(nt+2)+lo]
            const float up = __shfl_up(acc[nt + 2][3], 16);   // all lanes execute
            float pv;
            if (hi > 0)          pv = up;
            else if (wave > 0)   pv = xbuf[p][wave - 1][nt][lo];
            else if (tile > 0)   pv = xbuf[p ^ 1][WAVES - 1][nt][lo];
            else                 pv = 0.f;
            ob[32 * fbase + nt * 16 + lo] = acc[nt][0] + pv;

            #pragma unroll
            for (int r = 1; r < 4; ++r) {
                ob[32 * (fbase + r) + nt * 16 + lo] = acc[nt][r] + acc[nt + 2][r - 1];
            }
        }

        // last tile of a batch: trailing 32 samples get only C[15999][c+32]
        if (tile == TPBATCH - 1 && wave == WAVES - 1 && hi == 3) {
            ob[32 * FRAMES + 0 * 16 + lo] = acc[2][3];
            ob[32 * FRAMES + 1 * 16 + lo] = acc[3][3];
        }

        __syncthreads();   // protect xbuf reads from next tile's writes
    }
}

extern "C" void kernel_launch(void* const* d_in, const int* in_sizes, int n_in,
                              void* d_out, int out_size, void* d_ws, size_t ws_size,
                              hipStream_t stream) {
    const float* weight = (const float*)d_in[0];   // (8, 16000, 512) f32
    const float* basis  = (const float*)d_in[1];   // (64, 512) f32
    float* out = (float*)d_out;                    // (8, 512032) f32

    basis_ola_kernel<<<GRID, BLOCK, 0, stream>>>(weight, basis, out);
}